// Round 12
// baseline (774.644 us; speedup 1.0000x reference)
//
#include <hip/hip_runtime.h>

#define NN 50000
#define NE 800000
#define NT64 12500   // 64-edge tiles
#define E1B 1024
#define E1C 13       // 64-edge tiles per block (1024*13 >= 12500)

typedef _Float16 half8 __attribute__((ext_vector_type(8)));
typedef _Float16 half4 __attribute__((ext_vector_type(4)));
typedef float f32x4 __attribute__((ext_vector_type(4)));

__device__ __forceinline__ float sigm(float x) { return 1.0f / (1.0f + __expf(-x)); }

// ---------- zero cnt ----------
__global__ void zeroc_kernel(unsigned* __restrict__ cnt) {
  int i = blockIdx.x * 256 + threadIdx.x;
  if (i < NN) cnt[i] = 0u;
}

// ---------- prep: W (f32 [k][n] 128x128) -> W^T (f16 [n][k]) in ws ----------
__global__ void prepw_kernel(const float* __restrict__ w0, const float* __restrict__ w1,
                             const float* __restrict__ w2, _Float16* __restrict__ wt) {
  const float* w = blockIdx.x == 0 ? w0 : (blockIdx.x == 1 ? w1 : w2);
  _Float16* o = wt + blockIdx.x * 16384;
  int t = threadIdx.x;
  for (int it = 0; it < 64; ++it) {
    int flat = it * 256 + t;
    int k = flat >> 7, n = flat & 127;
    o[n * 128 + k] = (_Float16)w[flat];
  }
}

// ---------- degree histogram ----------
__global__ void hist_kernel(const int* __restrict__ eidx, unsigned* __restrict__ cnt) {
  int e = blockIdx.x * 256 + threadIdx.x;
  if (e < NE) atomicAdd(&cnt[eidx[2 * e]], 1u);
}

// ---------- exclusive prefix scan: cnt -> cursor & cstart ----------
__global__ __launch_bounds__(1024) void scan_kernel(const unsigned* __restrict__ cnt,
                                                    unsigned* __restrict__ cursor,
                                                    unsigned* __restrict__ cstart) {
  __shared__ unsigned part[1024];
  const int t = threadIdx.x;
  const int CH = 49;                  // 1024*49 = 50176 >= NN
  int base = t * CH;
  unsigned s = 0;
  for (int i = 0; i < CH; ++i) { int j = base + i; if (j < NN) s += cnt[j]; }
  part[t] = s;
  __syncthreads();
  for (int off = 1; off < 1024; off <<= 1) {
    unsigned v = (t >= off) ? part[t - off] : 0u;
    __syncthreads();
    part[t] += v;
    __syncthreads();
  }
  unsigned run = (t > 0) ? part[t - 1] : 0u;
  for (int i = 0; i < CH; ++i) {
    int j = base + i;
    if (j < NN) { cursor[j] = run; cstart[j] = run; run += cnt[j]; }
  }
}

// ---------- counting-sort: dr[e] = (dst, sorted slot) ----------
__global__ void scatter_kernel(const int* __restrict__ eidx, unsigned* __restrict__ cursor,
                               int2* __restrict__ dr) {
  int e = blockIdx.x * 256 + threadIdx.x;
  if (e >= NE) return;
  int s = eidx[2 * e], d = eidx[2 * e + 1];
  unsigned pos = atomicAdd(&cursor[s], 1u);
  dr[e] = make_int2(d, (int)pos);
}

// ---------- node GEMM: nh16 = f16(nf @ Wn + bn) ----------
__global__ __launch_bounds__(512, 2) void node_kernel(
    const float* __restrict__ nf, const _Float16* __restrict__ wnT,
    const float* __restrict__ bnp, _Float16* __restrict__ nh16) {
  __shared__ __align__(16) char wl[32768];
  __shared__ __align__(16) char tl[65536];

  const int t = threadIdx.x;
  const int lane = t & 63;
  const int wave = t >> 6;
  const int wm = wave >> 2;
  const int wn = wave & 3;

  for (int it = 0; it < 4; ++it) {
    int h8 = it * 512 + t;
    int n = h8 >> 4, k8 = h8 & 15;
    half8 v = *(const half8*)(wnT + n * 128 + k8 * 8);
    *(half8*)(wl + ((n * 256 + k8 * 16) ^ ((n & 7) << 4))) = v;
  }

  const int row0 = blockIdx.x * 256;
  for (int it = 0; it < 8; ++it) {
    int idx8 = it * 512 + t;
    int row = idx8 >> 4, col8 = idx8 & 15;
    int grow = row0 + row;
    half8 h;
    if (grow < NN) {
      const float4* s = (const float4*)(nf + (size_t)grow * 128 + col8 * 8);
      float4 a = s[0], b = s[1];
      h[0] = (_Float16)a.x; h[1] = (_Float16)a.y; h[2] = (_Float16)a.z; h[3] = (_Float16)a.w;
      h[4] = (_Float16)b.x; h[5] = (_Float16)b.y; h[6] = (_Float16)b.z; h[7] = (_Float16)b.w;
    } else {
#pragma unroll
      for (int j = 0; j < 8; ++j) h[j] = (_Float16)0.0f;
    }
    *(half8*)(tl + ((row * 256 + col8 * 16) ^ ((row & 7) << 4))) = h;
  }
  __syncthreads();

  const int c0 = wn * 32 + (lane & 15);
  const int arow = wm * 128 + (lane & 15);
  const int akb = (lane >> 4) * 16;

  f32x4 acc[8][2] = {};
#pragma unroll
  for (int ks = 0; ks < 4; ++ks) {
    int kb = ks * 64 + akb;
    half8 B0 = *(half8*)(wl + c0 * 256 + (kb ^ ((c0 & 7) << 4)));
    half8 B1 = *(half8*)(wl + (c0 + 16) * 256 + (kb ^ ((c0 & 7) << 4)));
#pragma unroll
    for (int mi = 0; mi < 8; ++mi) {
      int r = arow + mi * 16;
      half8 A = *(half8*)(tl + r * 256 + (kb ^ ((r & 7) << 4)));
      acc[mi][0] = __builtin_amdgcn_mfma_f32_16x16x32_f16(A, B0, acc[mi][0], 0, 0, 0);
      acc[mi][1] = __builtin_amdgcn_mfma_f32_16x16x32_f16(A, B1, acc[mi][1], 0, 0, 0);
    }
  }

  const float b0 = bnp[c0], b1 = bnp[c0 + 16];
#pragma unroll
  for (int mi = 0; mi < 8; ++mi) {
#pragma unroll
    for (int r = 0; r < 4; ++r) {
      int grow = row0 + wm * 128 + mi * 16 + (lane >> 4) * 4 + r;
      if (grow < NN) {
        nh16[(size_t)grow * 128 + c0] = (_Float16)(acc[mi][0][r] + b0);
        nh16[(size_t)grow * 128 + c0 + 16] = (_Float16)(acc[mi][1][r] + b1);
      }
    }
  }
}

// ---------- e1m: barrier-free message GEMM ----------
// Both W^T matrices staged in LDS ONCE (64KB, 1 barrier); afterwards every
// wave free-runs: 16 edges x 64 cols per wave (wave-pairs split the 128 cols).
// A fragments loaded per-lane straight from ef (each byte read once per wave;
// col-half partner hits L1). m = sigm(g)*f*nh16[dst] stored f16 at slot rank.
__global__ __launch_bounds__(512, 4) void e1m_kernel(
    const float* __restrict__ ef, const int2* __restrict__ dr,
    const _Float16* __restrict__ wgT, const _Float16* __restrict__ wfT,
    const float* __restrict__ bgp, const float* __restrict__ bfp,
    const _Float16* __restrict__ nh16, _Float16* __restrict__ ms) {
  __shared__ __align__(16) char bs[65536];   // gate [0,32K) | filt [32K,64K), swizzled

  const int t = threadIdx.x;
  const int lane = t & 63;
  const int wave = t >> 6;     // 0..7
  const int lc = lane & 15;
  const int q = lane >> 4;     // 0..3

  // stage both W^T matrices, swizzled (verified pattern)
  for (int it = 0; it < 8; ++it) {
    int h8 = it * 512 + t;                      // 0..4095 chunks of 8 halfs
    const _Float16* src = (h8 < 2048) ? wgT : wfT;
    int loc = h8 & 2047;
    int n = loc >> 4, k8 = loc & 15;
    half8 v = *(const half8*)(src + n * 128 + k8 * 8);
    int off = ((h8 < 2048) ? 0 : 32768) + n * 256 + k8 * 16;
    *(half8*)(bs + (off ^ ((n & 7) << 4))) = v;
  }

  const int grp = wave >> 1;   // 0..3 : 16-edge group within 64-edge tile
  const int ch = wave & 1;     // 0..1 : 64-col half
  const int colbase = ch * 64;

  float bgv[4], bfv[4];
#pragma unroll
  for (int ct = 0; ct < 4; ++ct) {
    bgv[ct] = bgp[colbase + ct * 16 + lc];
    bfv[ct] = bfp[colbase + ct * 16 + lc];
  }
  __syncthreads();   // the ONLY barrier

  int firstT = blockIdx.x * E1C;
  int lastT = firstT + E1C; if (lastT > NT64) lastT = NT64;

  for (int tile = firstT; tile < lastT; ++tile) {
    const int e0 = tile * 64 + grp * 16;

    // dst+rank for my 4 edges (edge = e0 + q*4 + j, C-layout rows)
    int2 dj[4];
#pragma unroll
    for (int j = 0; j < 4; ++j) dj[j] = dr[e0 + q * 4 + j];

    // A loads: row e0+lc, 4 k-chunks of 8 floats (full row covered by q x ks)
    const float* ar = ef + (size_t)(e0 + lc) * 128 + q * 8;
    float4 av[8];
#pragma unroll
    for (int ks = 0; ks < 4; ++ks) {
      av[2 * ks]     = *(const float4*)(ar + ks * 32);
      av[2 * ks + 1] = *(const float4*)(ar + ks * 32 + 4);
    }

    // nh gathers (depend only on dj; issued before MFMAs, consumed after)
    _Float16 nhv[16];
#pragma unroll
    for (int ct = 0; ct < 4; ++ct)
#pragma unroll
      for (int j = 0; j < 4; ++j)
        nhv[ct * 4 + j] = nh16[(size_t)dj[j].x * 128 + colbase + ct * 16 + lc];

    f32x4 ag[4] = {}, af[4] = {};
#pragma unroll
    for (int ks = 0; ks < 4; ++ks) {
      float4 a0 = av[2 * ks], a1 = av[2 * ks + 1];
      half8 A;
      A[0] = (_Float16)a0.x; A[1] = (_Float16)a0.y; A[2] = (_Float16)a0.z; A[3] = (_Float16)a0.w;
      A[4] = (_Float16)a1.x; A[5] = (_Float16)a1.y; A[6] = (_Float16)a1.z; A[7] = (_Float16)a1.w;
      int kb = ks * 64 + q * 16;
#pragma unroll
      for (int ct = 0; ct < 4; ++ct) {
        int col = colbase + ct * 16 + lc;
        int bx = col * 256 + (kb ^ ((col & 7) << 4));
        half8 Bg = *(half8*)(bs + bx);
        half8 Bf = *(half8*)(bs + 32768 + bx);
        ag[ct] = __builtin_amdgcn_mfma_f32_16x16x32_f16(A, Bg, ag[ct], 0, 0, 0);
        af[ct] = __builtin_amdgcn_mfma_f32_16x16x32_f16(A, Bf, af[ct], 0, 0, 0);
      }
    }

    // epilogue: m = sigm(gate)*filt*nh -> f16 at src-sorted slot
#pragma unroll
    for (int ct = 0; ct < 4; ++ct) {
      int col = colbase + ct * 16 + lc;
#pragma unroll
      for (int j = 0; j < 4; ++j) {
        float mv = sigm(ag[ct][j] + bgv[ct]) * (af[ct][j] + bfv[ct]) * (float)nhv[ct * 4 + j];
        ms[(size_t)dj[j].y * 128 + col] = (_Float16)mv;
      }
    }
  }
}

// ---------- e3: per-src wave streaming segment-sum + fused BN+ReLU ----------
// lane covers 4 cols (8B); lane pairs (lane, lane+32) split row parity;
// one wave load instruction covers 512B (two rows); shfl_xor(32) merge.
__global__ __launch_bounds__(512) void e3_kernel(
    const _Float16* __restrict__ ms,
    const unsigned* __restrict__ cstart, const unsigned* __restrict__ cnt,
    const _Float16* __restrict__ nh16,
    const float* __restrict__ gamma, const float* __restrict__ beta,
    const float* __restrict__ mean, const float* __restrict__ var,
    float* __restrict__ out) {
  int s = blockIdx.x * 8 + (threadIdx.x >> 6);
  if (s >= NN) return;
  const int lane = threadIdx.x & 63;
  const int cb = (lane & 31) * 4;     // 4-col base
  const int rp = lane >> 5;           // row parity

  const unsigned start = cstart[s];
  const int deg = (int)cnt[s];
  const unsigned end = start + (unsigned)deg;

  const _Float16* __restrict__ Mc = ms + cb;

  float a0 = 0.0f, a1 = 0.0f, a2 = 0.0f, a3 = 0.0f;
  unsigned p = start + rp;
  // unrolled: this lane handles rows p, p+2 per iter
  for (; p + 2 < end; p += 4) {
    half4 A = *(const half4*)(Mc + (size_t)p * 128);
    half4 B = *(const half4*)(Mc + (size_t)(p + 2) * 128);
    a0 += (float)A[0] + (float)B[0];
    a1 += (float)A[1] + (float)B[1];
    a2 += (float)A[2] + (float)B[2];
    a3 += (float)A[3] + (float)B[3];
  }
  if (p < end) {
    half4 A = *(const half4*)(Mc + (size_t)p * 128);
    a0 += (float)A[0]; a1 += (float)A[1]; a2 += (float)A[2]; a3 += (float)A[3];
  }

  // merge parity halves
  a0 += __shfl_xor(a0, 32);
  a1 += __shfl_xor(a1, 32);
  a2 += __shfl_xor(a2, 32);
  a3 += __shfl_xor(a3, 32);

  if (lane < 32) {
    float inv = deg > 0 ? 1.0f / (float)deg : 0.0f;
    half4 H = *(const half4*)(nh16 + (size_t)s * 128 + cb);
    float4 vv = *(const float4*)(var + cb);
    float4 gg = *(const float4*)(gamma + cb);
    float4 mm = *(const float4*)(mean + cb);
    float4 bb = *(const float4*)(beta + cb);
    float4 o;
    o.x = fmaxf(((float)H[0] + a0 * inv - mm.x) * rsqrtf(vv.x + 0.001f) * gg.x + bb.x, 0.0f);
    o.y = fmaxf(((float)H[1] + a1 * inv - mm.y) * rsqrtf(vv.y + 0.001f) * gg.y + bb.y, 0.0f);
    o.z = fmaxf(((float)H[2] + a2 * inv - mm.z) * rsqrtf(vv.z + 0.001f) * gg.z + bb.z, 0.0f);
    o.w = fmaxf(((float)H[3] + a3 * inv - mm.w) * rsqrtf(vv.w + 0.001f) * gg.w + bb.w, 0.0f);
    *(float4*)(out + (size_t)s * 128 + cb) = o;
  }
}

extern "C" void kernel_launch(void* const* d_in, const int* in_sizes, int n_in,
                              void* d_out, int out_size, void* d_ws, size_t ws_size,
                              hipStream_t stream) {
  const float* nf    = (const float*)d_in[0];
  const float* ef    = (const float*)d_in[1];
  const float* Wn    = (const float*)d_in[2];
  const float* bn    = (const float*)d_in[3];
  const float* Wg    = (const float*)d_in[4];
  const float* bg    = (const float*)d_in[5];
  const float* Wf    = (const float*)d_in[6];
  const float* bf    = (const float*)d_in[7];
  const float* gamma = (const float*)d_in[8];
  const float* beta  = (const float*)d_in[9];
  const float* mean  = (const float*)d_in[10];
  const float* var   = (const float*)d_in[11];
  const int*   eidx  = (const int*)d_in[12];
  float* out = (float*)d_out;
  char* ws = (char*)d_ws;

  _Float16* nh16   = (_Float16*)(ws + 0);            //  12,800,000
  _Float16* ms     = (_Float16*)(ws + 12800000);     // 204,800,000
  unsigned* cnt    = (unsigned*)(ws + 217600000);    //     200,000
  unsigned* cstart = (unsigned*)(ws + 217800000);    //     200,000
  unsigned* cursor = (unsigned*)(ws + 218000000);    //     200,000
  _Float16* wt     = (_Float16*)(ws + 218200000);    //      98,304
  int2*     dr     = (int2*)(ws + 218300000);        //   6,400,000 -> end 224,700,000

  zeroc_kernel<<<(NN + 255) / 256, 256, 0, stream>>>(cnt);
  prepw_kernel<<<3, 256, 0, stream>>>(Wn, Wg, Wf, wt);
  hist_kernel<<<NE / 256, 256, 0, stream>>>(eidx, cnt);
  scan_kernel<<<1, 1024, 0, stream>>>(cnt, cursor, cstart);
  scatter_kernel<<<NE / 256, 256, 0, stream>>>(eidx, cursor, dr);
  node_kernel<<<(NN + 255) / 256, 512, 0, stream>>>(nf, wt, bn, nh16);
  e1m_kernel<<<E1B, 512, 0, stream>>>(ef, dr, wt + 16384, wt + 32768,
                                      bg, bf, nh16, ms);
  e3_kernel<<<(NN + 7) / 8, 512, 0, stream>>>(ms, cstart, cnt, nh16,
                                              gamma, beta, mean, var, out);
}

// Round 13
// 465.054 us; speedup vs baseline: 1.6657x; 1.6657x over previous
//
#include <hip/hip_runtime.h>

#define NN 50000
#define NE 800000
#define NT 12500     // 64-edge tiles
#define E1B 1788     // e1 blocks
#define E1T 7        // tiles per e1 block (1788*7 >= 12500)

typedef _Float16 half8 __attribute__((ext_vector_type(8)));
typedef _Float16 half4 __attribute__((ext_vector_type(4)));
typedef float f32x4 __attribute__((ext_vector_type(4)));

__device__ __forceinline__ float sigm(float x) { return 1.0f / (1.0f + __expf(-x)); }

// ---------- zero cnt ----------
__global__ void zeroc_kernel(unsigned* __restrict__ cnt) {
  int i = blockIdx.x * 256 + threadIdx.x;
  if (i < NN) cnt[i] = 0u;
}

// ---------- prep: W (f32 [k][n] 128x128) -> W^T (f16 [n][k]) in ws ----------
__global__ void prepw_kernel(const float* __restrict__ w0, const float* __restrict__ w1,
                             const float* __restrict__ w2, _Float16* __restrict__ wt) {
  const float* w = blockIdx.x == 0 ? w0 : (blockIdx.x == 1 ? w1 : w2);
  _Float16* o = wt + blockIdx.x * 16384;
  int t = threadIdx.x;
  for (int it = 0; it < 64; ++it) {
    int flat = it * 256 + t;
    int k = flat >> 7, n = flat & 127;
    o[n * 128 + k] = (_Float16)w[flat];
  }
}

// ---------- degree histogram ----------
__global__ void hist_kernel(const int* __restrict__ eidx, unsigned* __restrict__ cnt) {
  int e = blockIdx.x * 256 + threadIdx.x;
  if (e < NE) atomicAdd(&cnt[eidx[2 * e]], 1u);
}

// ---------- exclusive prefix scan: cnt -> cursor & cstart ----------
__global__ __launch_bounds__(1024) void scan_kernel(const unsigned* __restrict__ cnt,
                                                    unsigned* __restrict__ cursor,
                                                    unsigned* __restrict__ cstart) {
  __shared__ unsigned part[1024];
  const int t = threadIdx.x;
  const int CH = 49;                  // 1024*49 = 50176 >= NN
  int base = t * CH;
  unsigned s = 0;
  for (int i = 0; i < CH; ++i) { int j = base + i; if (j < NN) s += cnt[j]; }
  part[t] = s;
  __syncthreads();
  for (int off = 1; off < 1024; off <<= 1) {
    unsigned v = (t >= off) ? part[t - off] : 0u;
    __syncthreads();
    part[t] += v;
    __syncthreads();
  }
  unsigned run = (t > 0) ? part[t - 1] : 0u;
  for (int i = 0; i < CH; ++i) {
    int j = base + i;
    if (j < NN) { cursor[j] = run; cstart[j] = run; run += cnt[j]; }
  }
}

// ---------- counting-sort scatter: (dst, eid) sorted by src ----------
__global__ void scatter_kernel(const int* __restrict__ eidx, unsigned* __restrict__ cursor,
                               int2* __restrict__ sed) {
  int e = blockIdx.x * 256 + threadIdx.x;
  if (e >= NE) return;
  int s = eidx[2 * e], d = eidx[2 * e + 1];
  unsigned pos = atomicAdd(&cursor[s], 1u);
  sed[pos] = make_int2(d, e);
}

// ---------- node GEMM: nh16 = f16(nf @ Wn + bn) ----------
__global__ __launch_bounds__(512, 2) void node_kernel(
    const float* __restrict__ nf, const _Float16* __restrict__ wnT,
    const float* __restrict__ bnp, _Float16* __restrict__ nh16) {
  __shared__ __align__(16) char wl[32768];
  __shared__ __align__(16) char tl[65536];

  const int t = threadIdx.x;
  const int lane = t & 63;
  const int wave = t >> 6;
  const int wm = wave >> 2;
  const int wn = wave & 3;

  for (int it = 0; it < 4; ++it) {
    int h8 = it * 512 + t;
    int n = h8 >> 4, k8 = h8 & 15;
    half8 v = *(const half8*)(wnT + n * 128 + k8 * 8);
    *(half8*)(wl + ((n * 256 + k8 * 16) ^ ((n & 7) << 4))) = v;
  }

  const int row0 = blockIdx.x * 256;
  for (int it = 0; it < 8; ++it) {
    int idx8 = it * 512 + t;
    int row = idx8 >> 4, col8 = idx8 & 15;
    int grow = row0 + row;
    half8 h;
    if (grow < NN) {
      const float4* s = (const float4*)(nf + (size_t)grow * 128 + col8 * 8);
      float4 a = s[0], b = s[1];
      h[0] = (_Float16)a.x; h[1] = (_Float16)a.y; h[2] = (_Float16)a.z; h[3] = (_Float16)a.w;
      h[4] = (_Float16)b.x; h[5] = (_Float16)b.y; h[6] = (_Float16)b.z; h[7] = (_Float16)b.w;
    } else {
#pragma unroll
      for (int j = 0; j < 8; ++j) h[j] = (_Float16)0.0f;
    }
    *(half8*)(tl + ((row * 256 + col8 * 16) ^ ((row & 7) << 4))) = h;
  }
  __syncthreads();

  const int c0 = wn * 32 + (lane & 15);
  const int arow = wm * 128 + (lane & 15);
  const int akb = (lane >> 4) * 16;

  f32x4 acc[8][2] = {};
#pragma unroll
  for (int ks = 0; ks < 4; ++ks) {
    int kb = ks * 64 + akb;
    half8 B0 = *(half8*)(wl + c0 * 256 + (kb ^ ((c0 & 7) << 4)));
    half8 B1 = *(half8*)(wl + (c0 + 16) * 256 + (kb ^ ((c0 & 7) << 4)));
#pragma unroll
    for (int mi = 0; mi < 8; ++mi) {
      int r = arow + mi * 16;
      half8 A = *(half8*)(tl + r * 256 + (kb ^ ((r & 7) << 4)));
      acc[mi][0] = __builtin_amdgcn_mfma_f32_16x16x32_f16(A, B0, acc[mi][0], 0, 0, 0);
      acc[mi][1] = __builtin_amdgcn_mfma_f32_16x16x32_f16(A, B1, acc[mi][1], 0, 0, 0);
    }
  }

  const float b0 = bnp[c0], b1 = bnp[c0 + 16];
#pragma unroll
  for (int mi = 0; mi < 8; ++mi) {
#pragma unroll
    for (int r = 0; r < 4; ++r) {
      int grow = row0 + wm * 128 + mi * 16 + (lane >> 4) * 4 + r;
      if (grow < NN) {
        nh16[(size_t)grow * 128 + c0] = (_Float16)(acc[mi][0][r] + b0);
        nh16[(size_t)grow * 128 + c0 + 16] = (_Float16)(acc[mi][1][r] + b1);
      }
    }
  }
}

// ---------- e1: streaming dual GEMM, B in regs, LDS dbuf, 1 barrier/tile ----------
// P[e] = sigm(ef[e]@Wg+bg) * (ef[e]@Wf+bf)  (f16, original edge order)  [R7 verbatim]
__global__ __launch_bounds__(512, 4) void e1_kernel(
    const float* __restrict__ ef,
    const _Float16* __restrict__ wgT, const _Float16* __restrict__ wfT,
    const float* __restrict__ bgp, const float* __restrict__ bfp,
    _Float16* __restrict__ P) {
  __shared__ __align__(16) char tl[2][16384];   // 64 edges x 128 f16, swizzled, dbuf

  const int t = threadIdx.x;
  const int lane = t & 63;
  const int w = t >> 6;        // wave 0..7 -> 16-col slice
  const int lc = lane & 15;
  const int q = lane >> 4;     // 0..3

  const int col = w * 16 + lc;
  half8 Bg[4], Bf[4];
#pragma unroll
  for (int ks = 0; ks < 4; ++ks) {
    Bg[ks] = *(const half8*)(wgT + (size_t)col * 128 + ks * 32 + q * 8);
    Bf[ks] = *(const half8*)(wfT + (size_t)col * 128 + ks * 32 + q * 8);
  }
  const float bgv = bgp[col], bfv = bfp[col];

  int first = blockIdx.x * E1T;
  int last = first + E1T; if (last > NT) last = NT;
  if (first >= NT) return;

  float4 r0a, r0b, r1a, r1b;   // staging registers

#define LOADR(tile)                                                              \
  {                                                                              \
    const float* b0_ = ef + (size_t)((tile) * 64 + (t >> 4)) * 128 + (t & 15) * 8; \
    r0a = *(const float4*)b0_; r0b = *(const float4*)(b0_ + 4);                  \
    const float* b1_ = b0_ + (size_t)32 * 128;                                   \
    r1a = *(const float4*)b1_; r1b = *(const float4*)(b1_ + 4);                  \
  }

#define WRITEB(bf_)                                                              \
  {                                                                              \
    int row_ = t >> 4, c16_ = (t & 15) * 16;                                     \
    half8 h_;                                                                    \
    h_[0]=(_Float16)r0a.x; h_[1]=(_Float16)r0a.y; h_[2]=(_Float16)r0a.z; h_[3]=(_Float16)r0a.w; \
    h_[4]=(_Float16)r0b.x; h_[5]=(_Float16)r0b.y; h_[6]=(_Float16)r0b.z; h_[7]=(_Float16)r0b.w; \
    *(half8*)(tl[bf_] + ((row_ * 256 + c16_) ^ ((row_ & 7) << 4))) = h_;         \
    row_ += 32;                                                                  \
    h_[0]=(_Float16)r1a.x; h_[1]=(_Float16)r1a.y; h_[2]=(_Float16)r1a.z; h_[3]=(_Float16)r1a.w; \
    h_[4]=(_Float16)r1b.x; h_[5]=(_Float16)r1b.y; h_[6]=(_Float16)r1b.z; h_[7]=(_Float16)r1b.w; \
    *(half8*)(tl[bf_] + ((row_ * 256 + c16_) ^ ((row_ & 7) << 4))) = h_;         \
  }

  LOADR(first);
  WRITEB(0);
  __syncthreads();
  int buf = 0;

  for (int i = first; i < last; ++i) {
    const bool more = (i + 1 < last);
    if (more) LOADR(i + 1);        // issue next-tile loads early (T14)

    f32x4 ag[4] = {}, af[4] = {};
#pragma unroll
    for (int ks = 0; ks < 4; ++ks) {
#pragma unroll
      for (int mi = 0; mi < 4; ++mi) {
        int r = mi * 16 + lc;
        half8 A = *(half8*)(tl[buf] + ((r * 256 + ks * 64 + q * 16) ^ ((r & 7) << 4)));
        ag[mi] = __builtin_amdgcn_mfma_f32_16x16x32_f16(A, Bg[ks], ag[mi], 0, 0, 0);
        af[mi] = __builtin_amdgcn_mfma_f32_16x16x32_f16(A, Bf[ks], af[mi], 0, 0, 0);
      }
    }

    _Float16* Pc = P + (size_t)i * 64 * 128 + col;
#pragma unroll
    for (int mi = 0; mi < 4; ++mi) {
#pragma unroll
      for (int rr = 0; rr < 4; ++rr) {
        int el = mi * 16 + q * 4 + rr;
        float pv = sigm(ag[mi][rr] + bgv) * (af[mi][rr] + bfv);
        Pc[(size_t)el * 128] = (_Float16)pv;
      }
    }

    if (more) WRITEB(buf ^ 1);
    __syncthreads();
    buf ^= 1;
  }
#undef LOADR
#undef WRITEB
}

// ---------- e2: per-src wave; parity-split gathers of P[eid] & nh16[dst] ----------
// lane covers 4 cols (8B); lane halves split row parity -> one wave load
// instruction fetches TWO 256B rows. shfl_xor(32) merge, float4 BN+ReLU out.
__global__ __launch_bounds__(512) void e2_kernel(
    const _Float16* __restrict__ P, const int2* __restrict__ sed,
    const unsigned* __restrict__ cstart, const unsigned* __restrict__ cnt,
    const _Float16* __restrict__ nh16,
    const float* __restrict__ gamma, const float* __restrict__ beta,
    const float* __restrict__ mean, const float* __restrict__ var,
    float* __restrict__ out) {
  int s = blockIdx.x * 8 + (threadIdx.x >> 6);
  if (s >= NN) return;
  const int lane = threadIdx.x & 63;
  const int cb = (lane & 31) * 4;     // 4-col base
  const int rp = lane >> 5;           // row parity

  const unsigned start = cstart[s];
  const int deg = (int)cnt[s];
  const unsigned end = start + (unsigned)deg;

  const _Float16* __restrict__ Pc = P + cb;
  const _Float16* __restrict__ Nc = nh16 + cb;

  float a0 = 0.0f, a1 = 0.0f, a2 = 0.0f, a3 = 0.0f;
  unsigned p = start + rp;
  for (; p + 2 < end; p += 4) {         // rows p and p+2 this iter
    int2 eA = sed[p];
    int2 eB = sed[p + 2];
    half4 PA = *(const half4*)(Pc + (size_t)eA.y * 128);
    half4 PB = *(const half4*)(Pc + (size_t)eB.y * 128);
    half4 NA = *(const half4*)(Nc + (size_t)eA.x * 128);
    half4 NB = *(const half4*)(Nc + (size_t)eB.x * 128);
    a0 += (float)PA[0] * (float)NA[0] + (float)PB[0] * (float)NB[0];
    a1 += (float)PA[1] * (float)NA[1] + (float)PB[1] * (float)NB[1];
    a2 += (float)PA[2] * (float)NA[2] + (float)PB[2] * (float)NB[2];
    a3 += (float)PA[3] * (float)NA[3] + (float)PB[3] * (float)NB[3];
  }
  if (p < end) {
    int2 eA = sed[p];
    half4 PA = *(const half4*)(Pc + (size_t)eA.y * 128);
    half4 NA = *(const half4*)(Nc + (size_t)eA.x * 128);
    a0 += (float)PA[0] * (float)NA[0];
    a1 += (float)PA[1] * (float)NA[1];
    a2 += (float)PA[2] * (float)NA[2];
    a3 += (float)PA[3] * (float)NA[3];
  }

  // merge parity halves
  a0 += __shfl_xor(a0, 32);
  a1 += __shfl_xor(a1, 32);
  a2 += __shfl_xor(a2, 32);
  a3 += __shfl_xor(a3, 32);

  if (lane < 32) {
    float inv = deg > 0 ? 1.0f / (float)deg : 0.0f;
    half4 H = *(const half4*)(Nc + (size_t)s * 128);
    float4 vv = *(const float4*)(var + cb);
    float4 gg = *(const float4*)(gamma + cb);
    float4 mm = *(const float4*)(mean + cb);
    float4 bb = *(const float4*)(beta + cb);
    float4 o;
    o.x = fmaxf(((float)H[0] + a0 * inv - mm.x) * rsqrtf(vv.x + 0.001f) * gg.x + bb.x, 0.0f);
    o.y = fmaxf(((float)H[1] + a1 * inv - mm.y) * rsqrtf(vv.y + 0.001f) * gg.y + bb.y, 0.0f);
    o.z = fmaxf(((float)H[2] + a2 * inv - mm.z) * rsqrtf(vv.z + 0.001f) * gg.z + bb.z, 0.0f);
    o.w = fmaxf(((float)H[3] + a3 * inv - mm.w) * rsqrtf(vv.w + 0.001f) * gg.w + bb.w, 0.0f);
    *(float4*)(out + (size_t)s * 128 + cb) = o;
  }
}

extern "C" void kernel_launch(void* const* d_in, const int* in_sizes, int n_in,
                              void* d_out, int out_size, void* d_ws, size_t ws_size,
                              hipStream_t stream) {
  const float* nf    = (const float*)d_in[0];
  const float* ef    = (const float*)d_in[1];
  const float* Wn    = (const float*)d_in[2];
  const float* bn    = (const float*)d_in[3];
  const float* Wg    = (const float*)d_in[4];
  const float* bg    = (const float*)d_in[5];
  const float* Wf    = (const float*)d_in[6];
  const float* bf    = (const float*)d_in[7];
  const float* gamma = (const float*)d_in[8];
  const float* beta  = (const float*)d_in[9];
  const float* mean  = (const float*)d_in[10];
  const float* var   = (const float*)d_in[11];
  const int*   eidx  = (const int*)d_in[12];
  float* out = (float*)d_out;
  char* ws = (char*)d_ws;

  _Float16* nh16   = (_Float16*)(ws + 0);            //  12,800,000
  _Float16* P16    = (_Float16*)(ws + 12800000);     // 204,800,000
  unsigned* cnt    = (unsigned*)(ws + 217600000);    //     200,000
  unsigned* cstart = (unsigned*)(ws + 217800000);    //     200,000
  unsigned* cursor = (unsigned*)(ws + 218000000);    //     200,000
  _Float16* wt     = (_Float16*)(ws + 218200000);    //      98,304
  int2*     sed    = (int2*)(ws + 218300000);        //   6,400,000  -> end 224,700,000

  zeroc_kernel<<<(NN + 255) / 256, 256, 0, stream>>>(cnt);
  prepw_kernel<<<3, 256, 0, stream>>>(Wn, Wg, Wf, wt);
  hist_kernel<<<NE / 256, 256, 0, stream>>>(eidx, cnt);
  scan_kernel<<<1, 1024, 0, stream>>>(cnt, cursor, cstart);
  scatter_kernel<<<NE / 256, 256, 0, stream>>>(eidx, cursor, sed);
  node_kernel<<<(NN + 255) / 256, 512, 0, stream>>>(nf, wt, bn, nh16);
  e1_kernel<<<E1B, 512, 0, stream>>>(ef, wt + 16384, wt + 32768, bg, bf, P16);
  e2_kernel<<<(NN + 7) / 8, 512, 0, stream>>>(P16, sed, cstart, cnt, nh16,
                                              gamma, beta, mean, var, out);
}